// Round 1
// baseline (1243.135 us; speedup 1.0000x reference)
//
#include <hip/hip_runtime.h>
#include <math.h>

#define T_STEPS 12
#define HID 64

__device__ __forceinline__ float sigmoidf_(float x){ return 1.0f/(1.0f + __expf(-x)); }
__device__ __forceinline__ float tanhf_(float x){
  float e = __expf(-2.0f * fabsf(x));
  float t = (1.0f - e) / (1.0f + e);
  return copysignf(t, x);
}

// --- CSR build ---------------------------------------------------------
__global__ void count_kernel(const int* __restrict__ ei, int E, int* __restrict__ cnt){
  int e = blockIdx.x*blockDim.x + threadIdx.x;
  if (e < E) atomicAdd(&cnt[ei[E + e]], 1);
}

__global__ void dinv_kernel(const int* __restrict__ cnt, float* __restrict__ dinv, int N){
  int i = blockIdx.x*blockDim.x + threadIdx.x;
  if (i < N) dinv[i] = 1.0f / sqrtf((float)cnt[i] + 1.0f);
}

// single-block exclusive scan (49 chunks of 1024)
__global__ void scan_kernel(const int* __restrict__ cnt, int* __restrict__ row_start,
                            int* __restrict__ cursor, int N){
  __shared__ int sm[1024];
  __shared__ int carry_s;
  int tid = threadIdx.x;
  if (tid == 0) carry_s = 0;
  __syncthreads();
  for (int base = 0; base < N; base += 1024){
    int v = (base+tid < N) ? cnt[base+tid] : 0;
    sm[tid] = v; __syncthreads();
    for (int off = 1; off < 1024; off <<= 1){
      int t = (tid >= off) ? sm[tid-off] : 0;
      __syncthreads();
      sm[tid] += t;
      __syncthreads();
    }
    int incl = sm[tid];
    int carry = carry_s;
    if (base+tid < N){
      int excl = carry + incl - v;
      row_start[base+tid] = excl;
      cursor[base+tid]    = excl;
    }
    __syncthreads();
    if (tid == 1023) carry_s = carry + sm[1023];
    __syncthreads();
  }
  if (tid == 0) row_start[N] = carry_s;
}

__global__ void fill_kernel(const int* __restrict__ ei, int E,
                            int* __restrict__ cursor, int* __restrict__ csr){
  int e = blockIdx.x*blockDim.x + threadIdx.x;
  if (e < E){
    int dst = ei[E + e];
    int pos = atomicAdd(&cursor[dst], 1);
    csr[pos] = ei[e];  // src
  }
}

// pack W (192x64 row-major) -> [k][j]{r,z,n,0} float4-friendly layout
__global__ void pack_kernel(const float* __restrict__ W_ih, const float* __restrict__ W_hh,
                            float* __restrict__ Wih_p, float* __restrict__ Whh_p){
  int idx = blockIdx.x*blockDim.x + threadIdx.x; // 0..16383
  int k = idx >> 8; int r = idx & 255; int j = r >> 2; int g = r & 3;
  float vi = 0.f, vh = 0.f;
  if (g < 3){
    vi = W_ih[(g*HID + j)*HID + k];
    vh = W_hh[(g*HID + j)*HID + k];
  }
  Wih_p[idx] = vi; Whh_p[idx] = vh;
}

// GCN aggregation in INPUT space, all 12 timesteps at once.
// rin[n][tc] = dinv[n] * sum_{e in in(n)} dinv[src]*x[src][tc] + dinv[n]^2 * x[n][tc]
__global__ void gather_kernel(const float* __restrict__ x, const int* __restrict__ row_start,
                              const int* __restrict__ csr, const float* __restrict__ dinv,
                              float* __restrict__ rin, int N){
  int lane = threadIdx.x & 63;
  int n = blockIdx.x*4 + (threadIdx.x >> 6);
  if (n >= N) return;
  int s0 = row_start[n], s1 = row_start[n+1];
  float acc = 0.f;
  for (int e = s0; e < s1; ++e){
    int s = csr[e];          // wave-uniform load
    float dv = dinv[s];      // wave-uniform load
    if (lane < 24) acc += dv * x[s*24 + lane];
  }
  if (lane < 24){
    float dn = dinv[n];
    float self = x[n*24 + lane];
    rin[n*24 + lane] = dn*acc + dn*dn*self;
  }
}

// One GRU step. Wave = 4 nodes; lane j = output channel j. No LDS, no barriers.
__global__ __launch_bounds__(256) void gru_kernel(
    const float* __restrict__ rin, int t,
    const float* __restrict__ W_gcn, const float* __restrict__ b_gcn,
    const float* __restrict__ Wih_p, const float* __restrict__ Whh_p,
    const float* __restrict__ b_ih, const float* __restrict__ b_hh,
    const float* __restrict__ h_in, float* __restrict__ h_out, int N){
  int lane = threadIdx.x & 63;
  int wid  = threadIdx.x >> 6;
  int n0 = (blockIdx.x*4 + wid)*4;
  float wg0 = W_gcn[lane], wg1 = W_gcn[HID+lane], bg = b_gcn[lane];
  float s[4], h[4];
  #pragma unroll
  for (int i = 0; i < 4; ++i){
    int n = n0 + i;
    if (n < N){
      float r0 = rin[n*24 + 2*t];
      float r1 = rin[n*24 + 2*t + 1];
      s[i] = fmaxf(fmaf(r0, wg0, fmaf(r1, wg1, bg)), 0.f);  // relu(spatial)
      h[i] = h_in[n*HID + lane];
    } else { s[i] = 0.f; h[i] = 0.f; }
  }
  float air[4]={0,0,0,0}, aiz[4]={0,0,0,0}, ain[4]={0,0,0,0};
  float ahr[4]={0,0,0,0}, ahz[4]={0,0,0,0}, ahn[4]={0,0,0,0};
  const float4* Wi4 = (const float4*)Wih_p;
  const float4* Wh4 = (const float4*)Whh_p;
  #pragma unroll 8
  for (int k = 0; k < HID; ++k){
    float4 wi = Wi4[k*HID + lane];
    float4 wh = Wh4[k*HID + lane];
    #pragma unroll
    for (int i = 0; i < 4; ++i){
      float sk = __shfl(s[i], k, 64);
      float hk = __shfl(h[i], k, 64);
      air[i] = fmaf(wi.x, sk, air[i]);
      aiz[i] = fmaf(wi.y, sk, aiz[i]);
      ain[i] = fmaf(wi.z, sk, ain[i]);
      ahr[i] = fmaf(wh.x, hk, ahr[i]);
      ahz[i] = fmaf(wh.y, hk, ahz[i]);
      ahn[i] = fmaf(wh.z, hk, ahn[i]);
    }
  }
  float bir = b_ih[lane], biz = b_ih[HID+lane], bin = b_ih[2*HID+lane];
  float bhr = b_hh[lane], bhz = b_hh[HID+lane], bhn = b_hh[2*HID+lane];
  #pragma unroll
  for (int i = 0; i < 4; ++i){
    int n = n0 + i;
    if (n < N){
      float r  = sigmoidf_(air[i] + bir + ahr[i] + bhr);
      float z  = sigmoidf_(aiz[i] + biz + ahz[i] + bhz);
      float nn = tanhf_(ain[i] + bin + r*(ahn[i] + bhn));
      h_out[n*HID + lane] = (1.0f - z)*nn + z*h[i];
    }
  }
}

__global__ void fc_kernel(const float* __restrict__ h, const float* __restrict__ W_fc,
                          const float* __restrict__ b_fc, float* __restrict__ out, int N){
  int lane = threadIdx.x & 63;
  int n = blockIdx.x*4 + (threadIdx.x >> 6);
  if (n >= N) return;
  float v = h[n*HID + lane] * W_fc[lane];
  #pragma unroll
  for (int m = 32; m >= 1; m >>= 1) v += __shfl_xor(v, m, 64);
  if (lane == 0) out[n] = v + b_fc[0];
}

extern "C" void kernel_launch(void* const* d_in, const int* in_sizes, int n_in,
                              void* d_out, int out_size, void* d_ws, size_t ws_size,
                              hipStream_t stream){
  const float* x     = (const float*)d_in[0];
  const int*   ei    = (const int*)d_in[1];
  const float* W_gcn = (const float*)d_in[2];
  const float* b_gcn = (const float*)d_in[3];
  const float* W_ih  = (const float*)d_in[4];
  const float* W_hh  = (const float*)d_in[5];
  const float* b_ih  = (const float*)d_in[6];
  const float* b_hh  = (const float*)d_in[7];
  const float* W_fc  = (const float*)d_in[8];
  const float* b_fc  = (const float*)d_in[9];
  float* out = (float*)d_out;
  const int N = in_sizes[0] / (T_STEPS*2);
  const int E = in_sizes[1] / 2;

  char* p = (char*)d_ws;
  auto alloc = [&](size_t bytes)->char*{
    char* r = p; p += (bytes + 255) & ~(size_t)255; return r;
  };
  int*   cnt       = (int*)  alloc((size_t)N*4);
  int*   row_start = (int*)  alloc((size_t)(N+1)*4);
  int*   cursor    = (int*)  alloc((size_t)N*4);
  int*   csr       = (int*)  alloc((size_t)E*4);
  float* dinv      = (float*)alloc((size_t)N*4);
  float* Wih_p     = (float*)alloc((size_t)64*256*4);
  float* Whh_p     = (float*)alloc((size_t)64*256*4);
  float* rin       = (float*)alloc((size_t)N*24*4);
  float* hA        = (float*)alloc((size_t)N*HID*4);
  float* hB        = (float*)alloc((size_t)N*HID*4);

  hipMemsetAsync(cnt, 0, (size_t)N*4, stream);
  count_kernel<<<(E+255)/256, 256, 0, stream>>>(ei, E, cnt);
  dinv_kernel<<<(N+255)/256, 256, 0, stream>>>(cnt, dinv, N);
  scan_kernel<<<1, 1024, 0, stream>>>(cnt, row_start, cursor, N);
  fill_kernel<<<(E+255)/256, 256, 0, stream>>>(ei, E, cursor, csr);
  pack_kernel<<<64, 256, 0, stream>>>(W_ih, W_hh, Wih_p, Whh_p);
  gather_kernel<<<(N+3)/4, 256, 0, stream>>>(x, row_start, csr, dinv, rin, N);
  hipMemsetAsync(hA, 0, (size_t)N*HID*4, stream);

  float* hin = hA; float* hout = hB;
  for (int t = 0; t < T_STEPS; ++t){
    gru_kernel<<<(N+15)/16, 256, 0, stream>>>(rin, t, W_gcn, b_gcn, Wih_p, Whh_p,
                                              b_ih, b_hh, hin, hout, N);
    float* tmp = hin; hin = hout; hout = tmp;
  }
  fc_kernel<<<(N+3)/4, 256, 0, stream>>>(hin, W_fc, b_fc, out, N);
}